// Round 4
// baseline (119.213 us; speedup 1.0000x reference)
//
#include <hip/hip_runtime.h>

// ---------------------------------------------------------------------------
// RandomForest: 100 trees, depth 5, D=256, B=8192, C=64.
//  * decision = sign(w.x + b); only node rows 0..15 route.
//  * ONE fused kernel: fp32->split-bf16 conversion in-register, GEMM
//    Z[8192x1600] = X.W^T (+bias) via 3-MFMA split emulation, traversal in
//    epilogue, near-ties (|z|<TAU) resolved inline with exact fp64 dot.
//  * 2 graph nodes total (forest_all + leaf_gather).
// ---------------------------------------------------------------------------

typedef __bf16 bf16;
typedef __attribute__((ext_vector_type(8))) __bf16 bf16x8;
typedef __attribute__((ext_vector_type(4))) float f32x4;

#define NTREES 100
#define NB     8192
#define ND     256
#define NNODES 31
#define NLEAF  32
#define NCLS   64
#define TAU    2.0e-3f
#define FQCAP  32

// ---- K1: fused GEMM + traversal + inline fixup ------------------------------
// block: 256 samples x 4 trees. 4 waves, each M=64 (mi=0..3), N=64 (ni=0..3).
__global__ __launch_bounds__(256, 3) void forest_all(
    const float* __restrict__ x,       // [8192][256]
    const float* __restrict__ wf,      // [100][31][256]
    const float* __restrict__ bias,    // [100][31]
    unsigned char* __restrict__ idxb)  // [8192][100]
{
    __shared__ char lds[50176];
    bf16*  Wh  = (bf16*)lds;               // [64 rows][128 k] swizzled, 16KB
    bf16*  Wl  = (bf16*)(lds + 16384);     // 16KB
    float* scr = (float*)(lds + 32768);    // [4 waves][64][17]  17.4KB
    __shared__ int fcnt;
    __shared__ unsigned short fitems[FQCAP];
    __shared__ unsigned char  fres[FQCAP];

    const int tid  = threadIdx.x;
    const int wave = tid >> 6;
    const int lane = tid & 63;
    const int m    = lane & 15;
    const int q    = lane >> 4;
    const int tg   = blockIdx.x;           // tree-group 0..24
    const int mg   = blockIdx.y;           // sample-tile 0..31 (256 samples)

    if (tid == 0) fcnt = 0;

    float biasv[4];
#pragma unroll
    for (int ni = 0; ni < 4; ++ni)
        biasv[ni] = bias[(size_t)(tg * 4 + ni) * NNODES + m];

    f32x4 acc[4][4];
#pragma unroll
    for (int mi = 0; mi < 4; ++mi)
#pragma unroll
        for (int ni = 0; ni < 4; ++ni)
            acc[mi][ni] = (f32x4){0.f, 0.f, 0.f, 0.f};

    // A base addresses: wave's sample rows are mg*256 + wave*64 + mi*16 + m
    const float* xbase[4];
#pragma unroll
    for (int mi = 0; mi < 4; ++mi)
        xbase[mi] = x + (size_t)(mg * 256 + wave * 64 + mi * 16 + m) * ND + q * 8;

    // B staging identity: thread covers row srow, k-octets c = (lane>>4)+4*it
    const int srow = wave * 16 + (lane & 15);
    const float* wrow = wf + ((size_t)(tg * 4 + (srow >> 4)) * NNODES + (srow & 15)) * ND;

#pragma unroll
    for (int kc = 0; kc < 2; ++kc) {
        __syncthreads();   // all waves done reading previous B half
        // ---- stage B half (64 rows x 128 k, hi+lo) from fp32 w, XOR-swizzled
#pragma unroll
        for (int it = 0; it < 4; ++it) {
            int c = (lane >> 4) + it * 4;            // k-octet 0..15
            const float* src = wrow + kc * 128 + c * 8;
            float4 f0 = *(const float4*)(src);
            float4 f1 = *(const float4*)(src + 4);
            float fv[8] = {f0.x, f0.y, f0.z, f0.w, f1.x, f1.y, f1.z, f1.w};
            bf16x8 h8, l8;
#pragma unroll
            for (int e = 0; e < 8; ++e) {
                bf16 h = (bf16)fv[e];
                h8[e] = h;
                l8[e] = (bf16)(fv[e] - (float)h);
            }
            int swz = c ^ (srow & 7);
            *(bf16x8*)(Wh + srow * 128 + swz * 8) = h8;
            *(bf16x8*)(Wl + srow * 128 + swz * 8) = l8;
        }
        __syncthreads();

        // ---- K-loop: 4 kk-steps; fp32 A prefetched one kk ahead, converted at use
        float4 ca[4], cb[4], na[4], nb2[4];
#pragma unroll
        for (int mi = 0; mi < 4; ++mi) {
            const float* p = xbase[mi] + kc * 128;
            ca[mi] = *(const float4*)p;
            cb[mi] = *(const float4*)(p + 4);
        }
#pragma unroll
        for (int kk = 0; kk < 4; ++kk) {
            if (kk < 3) {
#pragma unroll
                for (int mi = 0; mi < 4; ++mi) {
                    const float* p = xbase[mi] + kc * 128 + (kk + 1) * 32;
                    na[mi]  = *(const float4*)p;
                    nb2[mi] = *(const float4*)(p + 4);
                }
            }
            // convert current fp32 -> split bf16 frags
            bf16x8 ah[4], al[4];
#pragma unroll
            for (int mi = 0; mi < 4; ++mi) {
                float fv[8] = {ca[mi].x, ca[mi].y, ca[mi].z, ca[mi].w,
                               cb[mi].x, cb[mi].y, cb[mi].z, cb[mi].w};
#pragma unroll
                for (int e = 0; e < 8; ++e) {
                    bf16 h = (bf16)fv[e];
                    ah[mi][e] = h;
                    al[mi][e] = (bf16)(fv[e] - (float)h);
                }
            }
#pragma unroll
            for (int ni = 0; ni < 4; ++ni) {
                const int n    = ni * 16 + m;
                const int cidx = (4 * kk + q) ^ (m & 7);
                bf16x8 bh = *(const bf16x8*)(Wh + n * 128 + cidx * 8);
                bf16x8 bl = *(const bf16x8*)(Wl + n * 128 + cidx * 8);
#pragma unroll
                for (int mi = 0; mi < 4; ++mi) {
                    acc[mi][ni] = __builtin_amdgcn_mfma_f32_16x16x32_bf16(al[mi], bh, acc[mi][ni], 0, 0, 0);
                    acc[mi][ni] = __builtin_amdgcn_mfma_f32_16x16x32_bf16(ah[mi], bl, acc[mi][ni], 0, 0, 0);
                    acc[mi][ni] = __builtin_amdgcn_mfma_f32_16x16x32_bf16(ah[mi], bh, acc[mi][ni], 0, 0, 0);
                }
            }
#pragma unroll
            for (int mi = 0; mi < 4; ++mi) { ca[mi] = na[mi]; cb[mi] = nb2[mi]; }
        }
    }

    // ---- epilogue: per-tree LDS round-trip + traversal --------------------
    float* ws_ = scr + wave * (64 * 17);
    const int s_l = wave * 64 + lane;              // block-local sample 0..255
    const int sg  = mg * 256 + s_l;                // global sample
    unsigned int pk = 0;
#pragma unroll
    for (int ni = 0; ni < 4; ++ni) {
        // write: D row = q*4+r (sample within 16), col = m (node)
#pragma unroll
        for (int mi = 0; mi < 4; ++mi)
#pragma unroll
            for (int r = 0; r < 4; ++r)
                ws_[(mi * 16 + q * 4 + r) * 17 + m] = acc[mi][ni][r] + biasv[ni];
        __syncthreads();
        // walk: lane handles its sample row
        int node = 0;
        float mn = 1e30f;
#pragma unroll
        for (int lvl = 0; lvl < 5; ++lvl) {
            float z = ws_[lane * 17 + node];
            mn = fminf(mn, fabsf(z));
            node = 2 * node + (z <= 0.0f ? 1 : 0);
        }
        pk |= (unsigned)node << (8 * ni);
        if (mn < TAU) {
            int p = atomicAdd(&fcnt, 1);
            if (p < FQCAP) fitems[p] = (unsigned short)((s_l << 2) | ni);
        }
        __syncthreads();   // protect next ni's writes from this walk's reads
    }

    // ---- inline fixup: exact fp64 re-traversal of queued near-ties --------
    int cnt = fcnt;
    if (cnt > FQCAP) cnt = FQCAP;
    for (int i = wave; i < cnt; i += 4) {
        int it  = fitems[i];
        int sl2 = it >> 2, ni = it & 3;
        int t   = tg * 4 + ni;
        const float* xr = x + (size_t)(mg * 256 + sl2) * ND;
        float4 xv = *(const float4*)(xr + lane * 4);
        int node = 0;
        for (int lvl = 0; lvl < 5; ++lvl) {
            const float* wr = wf + ((size_t)t * NNODES + node) * ND;
            float4 wv = *(const float4*)(wr + lane * 4);
            double zz = (double)xv.x * wv.x + (double)xv.y * wv.y
                      + (double)xv.z * wv.z + (double)xv.w * wv.w;
#pragma unroll
            for (int o = 32; o > 0; o >>= 1) zz += __shfl_xor(zz, o);
            zz += (double)bias[t * NNODES + node];
            node = 2 * node + (zz <= 0.0 ? 1 : 0);
        }
        if (lane == 0) fres[i] = (unsigned char)node;
    }
    __syncthreads();

    // patch this thread's packed result with any fixups, then single store
    for (int i = 0; i < cnt; ++i) {
        int it = fitems[i];
        if ((it >> 2) == s_l) {
            int ni = it & 3;
            pk = (pk & ~(255u << (8 * ni))) | ((unsigned)fres[i] << (8 * ni));
        }
    }
    *(unsigned int*)(idxb + (size_t)sg * NTREES + tg * 4) = pk;
}

// ---- K2: leaf gather + forest mean (wave per sample, lane = class) ----------
__global__ void leaf_gather(const unsigned char* __restrict__ idxb,
                            const float* __restrict__ leaves,
                            float* __restrict__ out) {
    const int wave = threadIdx.x >> 6;
    const int lane = threadIdx.x & 63;
    const int s = blockIdx.x * 4 + wave;
    unsigned int rw = 0;
    if (lane < 25) rw = *(const unsigned int*)(idxb + (size_t)s * NTREES + lane * 4);
    float acc = 0.f;
#pragma unroll 10
    for (int t = 0; t < NTREES; ++t) {
        unsigned int wrd = __shfl(rw, t >> 2);
        int li = (wrd >> ((t & 3) * 8)) & 255;
        acc += leaves[((size_t)t * NLEAF + li) * NCLS + lane];
    }
    out[(size_t)s * NCLS + lane] = acc * 0.01f;
}

// ---------------------------------------------------------------------------
extern "C" void kernel_launch(void* const* d_in, const int* in_sizes, int n_in,
                              void* d_out, int out_size, void* d_ws, size_t ws_size,
                              hipStream_t stream) {
    const float* x  = (const float*)d_in[0];   // [8192,256]
    const float* nw = (const float*)d_in[1];   // [100,31,256]
    const float* nb = (const float*)d_in[2];   // [100,31]
    const float* lv = (const float*)d_in[3];   // [100,32,64]
    float* out = (float*)d_out;

    unsigned char* idxb = (unsigned char*)d_ws;   // 819,200 B
    if (ws_size < (size_t)819200) return;

    forest_all<<<dim3(NTREES / 4, NB / 256), 256, 0, stream>>>(x, nw, nb, idxb);
    leaf_gather<<<NB / 4, 256, 0, stream>>>(idxb, lv, out);
}

// Round 5
// 111.610 us; speedup vs baseline: 1.0681x; 1.0681x over previous
//
#include <hip/hip_runtime.h>

// ---------------------------------------------------------------------------
// RandomForest: 100 trees, depth 5, D=256, B=8192, C=64.
//  * decision = sign(w.x + b); routing reads only node rows 0..15.
//  * prep: X -> split-bf16 (hi/lo) in A-swizzled layout; W -> pre-swizzled
//    per-tree-group LDS image (hi|lo) in global.
//  * forest: Z[8192x1600] = X.W^T (+bias), 3-MFMA split emulation; B staging
//    is a pure 32KB copy; traversal in per-wave epilogue (LDS overlaid on B);
//    near-ties (|z|<TAU) resolved inline with exact fp64 dot.
// ---------------------------------------------------------------------------

typedef __bf16 bf16;
typedef __attribute__((ext_vector_type(8))) __bf16 bf16x8;
typedef __attribute__((ext_vector_type(4))) float f32x4;

#define NTREES 100
#define NB     8192
#define ND     256
#define NNODES 31
#define NLEAF  32
#define NCLS   64
#define TAU    2.0e-3f
#define FQCAP  32

// ---- K1: prep. blocks 0..1023: split X. blocks 1024..1223: W image. --------
// X layout: elem i = g*4096 + dq*128 + m*8 + e  ==  X[g*16+m][dq*8+e]
// W image (bf16 units, per tg 32768): kc*16384 + h*8192 + row*128 + cp*8,
//   cp = c ^ (row&7), data k-octet = kc*16 + c. Byte-identical to LDS image.
__global__ void prep(const float* __restrict__ x, const float* __restrict__ wf,
                     bf16* __restrict__ xh, bf16* __restrict__ xl,
                     bf16* __restrict__ wimg) {
    if (blockIdx.x < 1024) {
        int i = blockIdx.x * 256 + threadIdx.x;       // 0 .. 262143
        int m  = i & 15;
        int dq = (i >> 4) & 31;
        int g  = i >> 9;
        const float* src = x + (size_t)(g * 16 + m) * ND + dq * 8;
        bf16x8 h8, l8;
#pragma unroll
        for (int e = 0; e < 8; ++e) {
            float f = src[e];
            bf16 h = (bf16)f;
            h8[e] = h;
            l8[e] = (bf16)(f - (float)h);
        }
        *(bf16x8*)(xh + (size_t)i * 8) = h8;
        *(bf16x8*)(xl + (size_t)i * 8) = l8;
    } else {
        int i = (blockIdx.x - 1024) * 256 + threadIdx.x;  // 0..51199
        int oct = i & 31;            // k-octet 0..31
        int row = (i >> 5) & 63;     // B row 0..63
        int tg  = i >> 11;           // tree group 0..24
        int tree = tg * 4 + (row >> 4), node = row & 15;
        const float* src = wf + ((size_t)tree * NNODES + node) * ND + oct * 8;
        bf16x8 h8, l8;
#pragma unroll
        for (int e = 0; e < 8; ++e) {
            float f = src[e];
            bf16 h = (bf16)f;
            h8[e] = h;
            l8[e] = (bf16)(f - (float)h);
        }
        int kc = oct >> 4, c = oct & 15, cp = c ^ (row & 7);
        size_t b = (size_t)tg * 32768 + (size_t)kc * 16384 + row * 128 + cp * 8;
        *(bf16x8*)(wimg + b)        = h8;   // hi half
        *(bf16x8*)(wimg + b + 8192) = l8;   // lo half
    }
}

// ---- K2: GEMM + traversal + inline fixup ------------------------------------
// block: 256 samples x 4 trees. 4 waves, each M=64 (mi=0..3), N=64 (ni=0..3).
__global__ __launch_bounds__(256, 3) void forest_all(
    const bf16* __restrict__ xh, const bf16* __restrict__ xl,
    const bf16* __restrict__ wimg,
    const float* __restrict__ x,       // fp32, fixup only
    const float* __restrict__ wf,      // fp32, fixup only
    const float* __restrict__ bias,    // [100][31]
    unsigned char* __restrict__ idxb)  // [8192][100]
{
    __shared__ char lds[32768];            // B (hi 16KB | lo 16KB); scr overlays
    __shared__ int fcnt;
    __shared__ unsigned short fitems[FQCAP];
    __shared__ unsigned char  fres[FQCAP];
    bf16*  Wh  = (bf16*)lds;
    bf16*  Wl  = (bf16*)(lds + 16384);
    float* scr = (float*)lds;              // [4 waves][64][17] after K-loop

    const int tid  = threadIdx.x;
    const int wave = tid >> 6;
    const int lane = tid & 63;
    const int m    = lane & 15;
    const int q    = lane >> 4;
    const int tg   = blockIdx.x;           // tree-group 0..24
    const int mg   = blockIdx.y;           // sample-tile 0..31

    if (tid == 0) fcnt = 0;

    float biasv[4];
#pragma unroll
    for (int ni = 0; ni < 4; ++ni)
        biasv[ni] = bias[(size_t)(tg * 4 + ni) * NNODES + m];

    f32x4 acc[4][4];
#pragma unroll
    for (int mi = 0; mi < 4; ++mi)
#pragma unroll
        for (int ni = 0; ni < 4; ++ni)
            acc[mi][ni] = (f32x4){0.f, 0.f, 0.f, 0.f};

    // A frag base offsets (bf16 units): sample-group gbase+mi, lane part q*128+m*8
    size_t abase[4];
#pragma unroll
    for (int mi = 0; mi < 4; ++mi)
        abase[mi] = (size_t)(mg * 16 + wave * 4 + mi) * 4096 + lane * 8;

    const bf16* wsrc = wimg + (size_t)tg * 32768;

#pragma unroll
    for (int kc = 0; kc < 2; ++kc) {
        __syncthreads();   // previous half's B fully consumed
        // ---- stage B half: pure 32KB contiguous copy (hi+lo)
#pragma unroll
        for (int j = 0; j < 8; ++j) {
            int idx = j * 256 + tid;       // 0..2047 16B chunks
            *(bf16x8*)(lds + idx * 16) =
                *(const bf16x8*)(wsrc + (size_t)kc * 16384 + idx * 8);
        }
        __syncthreads();

        // ---- K-loop: 4 kk-steps, pure load->MFMA
#pragma unroll
        for (int kk = 0; kk < 4; ++kk) {
            bf16x8 ah[4], al[4];
#pragma unroll
            for (int mi = 0; mi < 4; ++mi) {
                size_t off = abase[mi] + (size_t)(kc * 16 + kk * 4) * 128;
                ah[mi] = *(const bf16x8*)(xh + off);
                al[mi] = *(const bf16x8*)(xl + off);
            }
#pragma unroll
            for (int ni = 0; ni < 4; ++ni) {
                const int n    = ni * 16 + m;
                const int cidx = (4 * kk + q) ^ (m & 7);
                bf16x8 bh = *(const bf16x8*)(Wh + n * 128 + cidx * 8);
                bf16x8 bl = *(const bf16x8*)(Wl + n * 128 + cidx * 8);
#pragma unroll
                for (int mi = 0; mi < 4; ++mi) {
                    acc[mi][ni] = __builtin_amdgcn_mfma_f32_16x16x32_bf16(al[mi], bh, acc[mi][ni], 0, 0, 0);
                    acc[mi][ni] = __builtin_amdgcn_mfma_f32_16x16x32_bf16(ah[mi], bl, acc[mi][ni], 0, 0, 0);
                    acc[mi][ni] = __builtin_amdgcn_mfma_f32_16x16x32_bf16(ah[mi], bh, acc[mi][ni], 0, 0, 0);
                }
            }
        }
    }
    __syncthreads();   // all waves done with B; LDS becomes per-wave scratch

    // ---- epilogue: per-wave LDS round-trip + traversal (no barriers needed:
    //      scr region is wave-private; in-wave LDS ordering via lgkmcnt)
    float* ws_ = scr + wave * 1088;                // 64 rows x 17
    const int s_l = wave * 64 + lane;              // block-local sample
    const int sg  = mg * 256 + s_l;                // global sample
    unsigned int pk = 0;
#pragma unroll
    for (int ni = 0; ni < 4; ++ni) {
        // D layout: row = q*4+r (sample within 16), col = m (node)
#pragma unroll
        for (int mi = 0; mi < 4; ++mi)
#pragma unroll
            for (int r = 0; r < 4; ++r)
                ws_[(mi * 16 + q * 4 + r) * 17 + m] = acc[mi][ni][r] + biasv[ni];
        int node = 0;
        float mn = 1e30f;
#pragma unroll
        for (int lvl = 0; lvl < 5; ++lvl) {
            float z = ws_[lane * 17 + node];       // reads nodes 0..15 only
            mn = fminf(mn, fabsf(z));
            node = 2 * node + (z <= 0.0f ? 1 : 0);
        }
        pk |= (unsigned)node << (8 * ni);
        if (mn < TAU) {
            int p = atomicAdd(&fcnt, 1);
            if (p < FQCAP) fitems[p] = (unsigned short)((s_l << 2) | ni);
        }
    }
    __syncthreads();   // all enqueues visible

    // ---- inline fixup: exact fp64 re-traversal of near-ties (one per wave)
    int cnt = fcnt;
    if (cnt > FQCAP) cnt = FQCAP;
    for (int i = wave; i < cnt; i += 4) {
        int it  = fitems[i];
        int sl2 = it >> 2, ni = it & 3;
        int t   = tg * 4 + ni;
        const float* xr = x + (size_t)(mg * 256 + sl2) * ND;
        float4 xv = *(const float4*)(xr + lane * 4);
        int node = 0;
        for (int lvl = 0; lvl < 5; ++lvl) {
            const float* wr = wf + ((size_t)t * NNODES + node) * ND;
            float4 wv = *(const float4*)(wr + lane * 4);
            double zz = (double)xv.x * wv.x + (double)xv.y * wv.y
                      + (double)xv.z * wv.z + (double)xv.w * wv.w;
#pragma unroll
            for (int o = 32; o > 0; o >>= 1) zz += __shfl_xor(zz, o);
            zz += (double)bias[t * NNODES + node];
            node = 2 * node + (zz <= 0.0 ? 1 : 0);
        }
        if (lane == 0) fres[i] = (unsigned char)node;
    }
    __syncthreads();

    for (int i = 0; i < cnt; ++i) {
        int it = fitems[i];
        if ((it >> 2) == s_l) {
            int ni = it & 3;
            pk = (pk & ~(255u << (8 * ni))) | ((unsigned)fres[i] << (8 * ni));
        }
    }
    *(unsigned int*)(idxb + (size_t)sg * NTREES + tg * 4) = pk;
}

// ---- K3: leaf gather + forest mean (wave per sample, lane = class) ----------
__global__ void leaf_gather(const unsigned char* __restrict__ idxb,
                            const float* __restrict__ leaves,
                            float* __restrict__ out) {
    const int wave = threadIdx.x >> 6;
    const int lane = threadIdx.x & 63;
    const int s = blockIdx.x * 4 + wave;
    unsigned int rw = 0;
    if (lane < 25) rw = *(const unsigned int*)(idxb + (size_t)s * NTREES + lane * 4);
    float acc = 0.f;
#pragma unroll 10
    for (int t = 0; t < NTREES; ++t) {
        unsigned int wrd = __shfl(rw, t >> 2);
        int li = (wrd >> ((t & 3) * 8)) & 255;
        acc += leaves[((size_t)t * NLEAF + li) * NCLS + lane];
    }
    out[(size_t)s * NCLS + lane] = acc * 0.01f;
}

// ---------------------------------------------------------------------------
extern "C" void kernel_launch(void* const* d_in, const int* in_sizes, int n_in,
                              void* d_out, int out_size, void* d_ws, size_t ws_size,
                              hipStream_t stream) {
    const float* x  = (const float*)d_in[0];   // [8192,256]
    const float* nw = (const float*)d_in[1];   // [100,31,256]
    const float* nb = (const float*)d_in[2];   // [100,31]
    const float* lv = (const float*)d_in[3];   // [100,32,64]
    float* out = (float*)d_out;

    char* ws = (char*)d_ws;
    bf16* xh   = (bf16*)(ws + 0);                           // 4,194,304
    bf16* xl   = (bf16*)(ws + 4194304);                     // 4,194,304
    bf16* wimg = (bf16*)(ws + 8388608);                     // 1,638,400
    unsigned char* idxb = (unsigned char*)(ws + 10027008);  //   819,200
    if (ws_size < (size_t)10846208) return;

    prep<<<1224, 256, 0, stream>>>(x, nw, xh, xl, wimg);
    forest_all<<<dim3(NTREES / 4, NB / 256), 256, 0, stream>>>(
        xh, xl, wimg, x, nw, nb, idxb);
    leaf_gather<<<NB / 4, 256, 0, stream>>>(idxb, lv, out);
}